// Round 19
// baseline (2166.222 us; speedup 1.0000x reference)
//
#include <hip/hip_runtime.h>
#include <hip/hip_bf16.h>
#include <math.h>

typedef __bf16 bf16_t;
typedef __bf16 bf16x4 __attribute__((ext_vector_type(4)));
typedef __bf16 bf16x8 __attribute__((ext_vector_type(8)));
typedef float  f32x4  __attribute__((ext_vector_type(4)));

#define TOKENS 8192
#define DIMV   768
#define INNERV 768
#define QKVW   2304
#define MLPW   3072
#define NSEQ   1024
#define NB     8
#define NH     12
#define DH     64

enum { EP_STORE = 0, EP_BIAS_RES = 1, EP_BIAS_GELU = 2 };

// async global->LDS DMA, 16B per lane. LDS dest must be wave-uniform base + lane*16.
__device__ __forceinline__ void gload_lds16(const bf16_t* g, bf16_t* l)
{
  __builtin_amdgcn_global_load_lds((const __attribute__((address_space(1))) void*)g,
                                   (__attribute__((address_space(3))) void*)l,
                                   16, 0, 0);
}

// exact-to-1.5e-7 gelu via A&S 7.1.26 erf.
__device__ __forceinline__ float gelu_fast(float x)
{
  const float z = fabsf(x) * 0.70710678118654752f;
  const float d = fmaf(0.3275911f, z, 1.0f);
#if __has_builtin(__builtin_amdgcn_rcpf)
  const float t = __builtin_amdgcn_rcpf(d);
#else
  const float t = 1.0f / d;
#endif
  float p = fmaf(t, 1.061405429f, -1.453152027f);
  p = fmaf(t, p, 1.421413741f);
  p = fmaf(t, p, -0.284496736f);
  p = fmaf(t, p, 0.254829592f);
  p = t * p;
  const float e = __expf(-z * z);
  float erfv = fmaf(-p, e, 1.0f);              // erf(|x|/sqrt(2)), >=0
  erfv = copysignf(erfv, x);
  return 0.5f * x * (1.0f + erfv);
}

// ---------------- GEMM: C[M,N] = s * (A[M,K] * B[N,K]^T) + bias, bf16 in, f32 acc ----
// BMx128 tile, BK=32, triple-buffered LDS, counted-vmcnt 1-barrier pipeline with
// EARLY stage (issue tile t+2 right after the iter-t barrier -> 2 K-steps of cover).
// Coalesced epilogue through aliased LDS.
// r19: grid axes SWAPPED (blockIdx.x = bn, blockIdx.y = bm) so blocks sharing an
// A-panel (the large activation operand) are dispatch-adjacent -> A-panel L2 reuse.
// B panels (weights, <=4.7MB total) stay L2-resident regardless. Bit-identical.
template <int BM>
__global__ __launch_bounds__(256)
void gemm_nt(const bf16_t* __restrict__ A, const bf16_t* __restrict__ B,
             const int K, const int N, const int mode,
             const float* __restrict__ sacc_p, const float sinvn, const float sbias,
             const float* __restrict__ bias,
             float* __restrict__ resid,
             bf16_t* __restrict__ outb,
             float* __restrict__ fout)   // if non-null (EP_BIAS_RES): fout = resid + v + bias
{
  constexpr int MI = BM / 32;            // acc rows of 16x16 frags per wave (4 or 2)
  constexpr int WR = BM / 2;             // wave-tile rows
  __shared__ __align__(16) bf16_t lsAll[3 * BM * 32 + 3 * 128 * 32];
  bf16_t* lsA = lsAll;                   // [3][BM*32]
  bf16_t* lsB = lsAll + 3 * BM * 32;     // [3][128*32]
  const int tid  = threadIdx.x;
  const int lane = tid & 63;
  const int wave = tid >> 6;
  const int wm = wave >> 1, wn = wave & 1;
  const int bn = blockIdx.x, bm = blockIdx.y;   // SWAPPED: bn fastest -> A-panel reuse

  const int srB   = wave * 32 + (lane >> 2);
  const int fswB  = (srB >> 1) & 3;
  const int scolB = ((lane & 3) ^ fswB) * 8;
  const bf16_t* gB = B + (size_t)(bn * 128 + srB) * K + scolB;
  const int lb0 = srB * 32 + (lane & 3) * 8;
  const int lb1 = (srB + 16) * 32 + (lane & 3) * 8;

  const int srA   = (BM == 128) ? srB : (wave * 16 + (lane >> 2));
  const int fswA  = (srA >> 1) & 3;
  const int scolA = ((lane & 3) ^ fswA) * 8;
  const bf16_t* gA = A + (size_t)(bm * BM + srA) * K + scolA;
  const int la0 = srA * 32 + (lane & 3) * 8;
  const int la1 = (srA + 16) * 32 + (lane & 3) * 8;   // BM==128 only

  f32x4 acc[MI][4];
#pragma unroll
  for (int i = 0; i < MI; i++)
#pragma unroll
    for (int j = 0; j < 4; j++) acc[i][j] = (f32x4){0.f, 0.f, 0.f, 0.f};

  const int fr   = ((lane & 15) >> 1) & 3;
  const int rsl  = ((lane >> 4) ^ fr) * 8;
  const int arow = (wm * WR + (lane & 15)) * 32 + rsl;
  const int brow = (wn * 64 + (lane & 15)) * 32 + rsl;

  auto stage = [&](int b, int kb) {
    gload_lds16(gA + kb, &lsA[b * BM * 32 + la0]);
    if constexpr (BM == 128) gload_lds16(gA + (size_t)16 * K + kb, &lsA[b * BM * 32 + la1]);
    gload_lds16(gB + kb, &lsB[b * 128 * 32 + lb0]);
    gload_lds16(gB + (size_t)16 * K + kb, &lsB[b * 128 * 32 + lb1]);
  };
  auto compute = [&](int b) {
    bf16x8 af[MI], bfv[4];
#pragma unroll
    for (int i = 0; i < MI; i++) af[i]  = *(const bf16x8*)&lsA[b * BM * 32 + arow + i * 16 * 32];
#pragma unroll
    for (int j = 0; j < 4; j++)  bfv[j] = *(const bf16x8*)&lsB[b * 128 * 32 + brow + j * 16 * 32];
#pragma unroll
    for (int i = 0; i < MI; i++)
#pragma unroll
      for (int j = 0; j < 4; j++)
        acc[i][j] = __builtin_amdgcn_mfma_f32_16x16x32_bf16(af[i], bfv[j], acc[i][j], 0, 0, 0);
  };

  const int NT = K / 32;
  stage(0, 0);
  stage(1, 32);
  int cb = 0, sb = 2;
  for (int t = 0; t < NT - 1; ++t) {
    if constexpr (BM == 128) asm volatile("s_waitcnt vmcnt(4)" ::: "memory");
    else                     asm volatile("s_waitcnt vmcnt(3)" ::: "memory");
    __builtin_amdgcn_s_barrier();
    __builtin_amdgcn_sched_barrier(0);                 // nothing hoists above barrier
    if (t + 2 < NT) stage(sb, (t + 2) * 32);           // issue EARLY: 2 K-steps of cover
    compute(cb);
    cb = (cb == 2) ? 0 : cb + 1;
    sb = (sb == 2) ? 0 : sb + 1;
  }
  asm volatile("s_waitcnt vmcnt(0)" ::: "memory");
  __builtin_amdgcn_s_barrier();
  __builtin_amdgcn_sched_barrier(0);
  compute(cb);

  // ---------------- coalesced epilogue via LDS ----------------
  __syncthreads();                       // all waves done with K-loop LDS reads
  const float s = (*sacc_p) * sinvn + sbias;
  const int lr0 = wm * WR + (lane >> 4) * 4;   // local row base of this thread's frags
  const int lc0 = wn * 64 + (lane & 15);       // local col base

  if (mode == EP_BIAS_RES) {
    float* ep = (float*)lsAll;
#pragma unroll
    for (int i = 0; i < MI; i++)
#pragma unroll
      for (int j = 0; j < 4; j++) {
        const float bcol = bias[bn * 128 + lc0 + j * 16];
#pragma unroll
        for (int r = 0; r < 4; r++)
          ep[(lr0 + i * 16 + r) * 132 + lc0 + j * 16] = acc[i][j][r] * s + bcol;
      }
    __syncthreads();
#pragma unroll
    for (int it = 0; it < BM / 8; ++it) {
      const int lr = it * 8 + (tid >> 5);
      const int lc = (tid & 31) * 4;
      f32x4 v = *(const f32x4*)&ep[lr * 132 + lc];
      const size_t idx = (size_t)(bm * BM + lr) * N + bn * 128 + lc;
      f32x4 rv = *(const f32x4*)&resid[idx];
      if (fout) *(f32x4*)&fout[idx]  = rv + v;   // final-layer fused output
      else      *(f32x4*)&resid[idx] = rv + v;
    }
  } else {
    bf16_t* ep = lsAll;
#pragma unroll
    for (int i = 0; i < MI; i++)
#pragma unroll
      for (int j = 0; j < 4; j++) {
        const int col = bn * 128 + lc0 + j * 16;
#pragma unroll
        for (int r = 0; r < 4; r++) {
          const float v = acc[i][j][r] * s;
          ep[(lr0 + i * 16 + r) * 136 + lc0 + j * 16] =
              (mode == EP_STORE) ? (bf16_t)v : (bf16_t)gelu_fast(v + bias[col]);
        }
      }
    __syncthreads();
#pragma unroll
    for (int it = 0; it < BM / 16; ++it) {
      const int lr = it * 16 + (tid >> 4);
      const int lc = (tid & 15) * 8;
      bf16x8 v = *(const bf16x8*)&ep[lr * 136 + lc];
      *(bf16x8*)&outb[(size_t)(bm * BM + lr) * N + bn * 128 + lc] = v;
    }
  }
}

// ---------------- LayerNorm: block-per-row, input register-cached (r18) ----------------
template <typename TIN, int W>
__global__ __launch_bounds__(256)
void ln_kern(const TIN* __restrict__ x, const float* __restrict__ g,
             const float* __restrict__ b, bf16_t* __restrict__ y)
{
  constexpr int NV4 = W / 4;                 // vec4s per row (192 or 768)
  constexpr int NV  = (NV4 + 255) / 256;     // vec4s per thread (1 or 3)
  const int row = blockIdx.x;
  const int tid = threadIdx.x;
  const TIN* xr = x + (size_t)row * W;
  f32x4 cache[NV];
  float s = 0.f, s2 = 0.f;
#pragma unroll
  for (int v = 0; v < NV; v++) {
    const int idx = v * 256 + tid;
    if (idx < NV4) {
      f32x4 f;
      if constexpr (sizeof(TIN) == 4) {
        f = ((const f32x4*)xr)[idx];
      } else {
        bf16x4 bv = ((const bf16x4*)xr)[idx];
#pragma unroll
        for (int e = 0; e < 4; e++) f[e] = (float)bv[e];
      }
      cache[v] = f;
#pragma unroll
      for (int e = 0; e < 4; e++) { s += f[e]; s2 += f[e] * f[e]; }
    }
  }
#pragma unroll
  for (int off = 32; off > 0; off >>= 1) {
    s  += __shfl_xor(s,  off, 64);
    s2 += __shfl_xor(s2, off, 64);
  }
  __shared__ float red[8];
  if ((tid & 63) == 0) { red[(tid >> 6) * 2] = s; red[(tid >> 6) * 2 + 1] = s2; }
  __syncthreads();
  const float ts  = red[0] + red[2] + red[4] + red[6];
  const float ts2 = red[1] + red[3] + red[5] + red[7];
  const float invW = 1.0f / (float)W;
  const float mean = ts * invW;
  const float var  = fmaxf(ts2 * invW - mean * mean, 0.f);
  const float rs   = rsqrtf(var + 1e-5f);
  bf16x4* yv = (bf16x4*)(y + (size_t)row * W);
  const f32x4* gv = (const f32x4*)g;
  const f32x4* bv4 = (const f32x4*)b;
#pragma unroll
  for (int v = 0; v < NV; v++) {
    const int idx = v * 256 + tid;
    if (idx < NV4) {
      f32x4 f = cache[v], gg = gv[idx], bb = bv4[idx];
      bf16x4 o;
#pragma unroll
      for (int e = 0; e < 4; e++) o[e] = (bf16_t)((f[e] - mean) * rs * gg[e] + bb[e]);
      yv[idx] = o;
    }
  }
}

// ---------------- MFMA flash attention, 8-wave QBLK=128 (unchanged) ----------------
__global__ __launch_bounds__(512)
void attn_mfma(const bf16_t* __restrict__ qkv, bf16_t* __restrict__ o)
{
  __shared__ __align__(16) bf16_t Ks[64][72];      // K [kv][d], +8 pad
  __shared__ __align__(16) bf16_t Vt[64][72];      // V^T [d][kv], +8 pad
  __shared__ __align__(16) bf16_t Pw[8][16][72];   // per-wave P [q][kv], +8 pad
  const float SCL = 0.125f * 1.44269504088896f;    // scale * log2(e)
  const int tid  = threadIdx.x;
  const int lane = tid & 63;
  const int wave = tid >> 6;                       // 0..7
  const int quad = lane >> 4;
  const int l15  = lane & 15;

  // XCD-aware decomposition (bijective: 768 = 8 * 96)
  const int id      = blockIdx.x;
  const int logical = (id & 7) * 96 + (id >> 3);
  const int qb   = logical & 7;                    // 0..7 (128 q rows each)
  const int rest = logical >> 3;                   // 0..95
  const int hh   = rest % 12;
  const int bb   = rest / 12;
  const size_t tokbase = (size_t)bb * NSEQ;

  const int qrow = qb * 128 + wave * 16 + l15;
  bf16x8 qf[2];
  {
    const bf16_t* qp = qkv + (tokbase + qrow) * QKVW + hh * DH;
    qf[0] = *(const bf16x8*)(qp + quad * 8);
    qf[1] = *(const bf16x8*)(qp + 32 + quad * 8);
  }

  f32x4 Ot[4];
#pragma unroll
  for (int i = 0; i < 4; i++) Ot[i] = (f32x4){0.f, 0.f, 0.f, 0.f};
  float m2[4], lp[4];                // m in log2 units; lp = lane-partial denom
#pragma unroll
  for (int r = 0; r < 4; r++) { m2[r] = -1e30f; lp[r] = 0.f; }

  const int srow = tid & 63;                       // kv row
  const int sd   = (tid >> 6) * 8;                 // d-base (0..56 step 8)

  bf16x8 k0, v0;
  {
    const bf16_t* kp = qkv + (tokbase + srow) * QKVW + INNERV + hh * DH + sd;
    k0 = *(const bf16x8*)kp;
    v0 = *(const bf16x8*)(kp + INNERV);
  }

  for (int kt = 0; kt < NSEQ / 64; ++kt) {
    __syncthreads();                 // all waves done reading prev tile's Ks/Vt
    *(bf16x8*)&Ks[srow][sd] = k0;
#pragma unroll
    for (int e = 0; e < 8; e++) Vt[sd + e][srow] = v0[e];
    __syncthreads();

    // issue next tile's loads NOW — in flight across the whole compute phase (T14)
    bf16x8 nk0 = k0, nv0 = v0;
    if (kt + 1 < NSEQ / 64) {
      const bf16_t* kp = qkv + (tokbase + (kt + 1) * 64 + srow) * QKVW + INNERV + hh * DH + sd;
      nk0 = *(const bf16x8*)kp;
      nv0 = *(const bf16x8*)(kp + INNERV);
    }

    f32x4 st[4];
    __builtin_amdgcn_s_setprio(1);
#pragma unroll
    for (int nt = 0; nt < 4; nt++) {
      bf16x8 b0 = *(const bf16x8*)&Ks[nt * 16 + l15][quad * 8];
      bf16x8 b1 = *(const bf16x8*)&Ks[nt * 16 + l15][32 + quad * 8];
      f32x4 c = (f32x4){0.f, 0.f, 0.f, 0.f};
      c = __builtin_amdgcn_mfma_f32_16x16x32_bf16(qf[0], b0, c, 0, 0, 0);
      c = __builtin_amdgcn_mfma_f32_16x16x32_bf16(qf[1], b1, c, 0, 0, 0);
      st[nt] = c;
    }
    __builtin_amdgcn_s_setprio(0);

    // lane-local maxima; global check via __all (== old global-rmax check)
    float lm[4];
#pragma unroll
    for (int r = 0; r < 4; r++)
      lm[r] = fmaxf(fmaxf(st[0][r], st[1][r]), fmaxf(st[2][r], st[3][r]));
    const bool ok = (lm[0] * SCL <= m2[0] + 8.f) && (lm[1] * SCL <= m2[1] + 8.f) &&
                    (lm[2] * SCL <= m2[2] + 8.f) && (lm[3] * SCL <= m2[3] + 8.f);
    if (!__all(ok)) {                 // slow path: true row-max reduce + rescale
#pragma unroll
      for (int r = 0; r < 4; r++) {
        float v = lm[r];
        v = fmaxf(v, __shfl_xor(v, 1, 64));
        v = fmaxf(v, __shfl_xor(v, 2, 64));
        v = fmaxf(v, __shfl_xor(v, 4, 64));
        v = fmaxf(v, __shfl_xor(v, 8, 64));
        const float rmax2 = v * SCL;
        const float mnew = fmaxf(m2[r], rmax2);
        const float alpha = exp2f(m2[r] - mnew);
        m2[r] = mnew;
        lp[r] *= alpha;
#pragma unroll
        for (int dt = 0; dt < 4; dt++) Ot[dt][r] *= alpha;
      }
    }
#pragma unroll
    for (int nt = 0; nt < 4; nt++) {
#pragma unroll
      for (int r = 0; r < 4; r++) {
        const float p = exp2f(fmaf(st[nt][r], SCL, -m2[r]));
        lp[r] += p;
        Pw[wave][quad * 4 + r][nt * 16 + l15] = (bf16_t)p;
      }
    }

    // Pw slab is WAVE-PRIVATE: own-wave LDS drain suffices (no block barrier).
    asm volatile("s_waitcnt lgkmcnt(0)" ::: "memory");
    __builtin_amdgcn_sched_barrier(0);

    __builtin_amdgcn_s_setprio(1);
#pragma unroll
    for (int kk = 0; kk < 2; kk++) {
      bf16x8 pa = *(const bf16x8*)&Pw[wave][l15][kk * 32 + quad * 8];
#pragma unroll
      for (int dt = 0; dt < 4; dt++) {
        bf16x8 vb = *(const bf16x8*)&Vt[dt * 16 + l15][kk * 32 + quad * 8];
        Ot[dt] = __builtin_amdgcn_mfma_f32_16x16x32_bf16(pa, vb, Ot[dt], 0, 0, 0);
      }
    }
    __builtin_amdgcn_s_setprio(0);

    k0 = nk0; v0 = nv0;
  }

  float inv[4];
#pragma unroll
  for (int r = 0; r < 4; r++) {
    float v = lp[r];
    v += __shfl_xor(v, 1, 64);
    v += __shfl_xor(v, 2, 64);
    v += __shfl_xor(v, 4, 64);
    v += __shfl_xor(v, 8, 64);
    inv[r] = 1.0f / v;
  }
#pragma unroll
  for (int dt = 0; dt < 4; dt++) {
#pragma unroll
    for (int r = 0; r < 4; r++) {
      const int q = qb * 128 + wave * 16 + quad * 4 + r;
      const int d = dt * 16 + l15;
      o[(tokbase + q) * INNERV + hh * DH + d] = (bf16_t)(Ot[dt][r] * inv[r]);
    }
  }
}

// ---------------- ternary quant helpers (f32 weights in), batched x4 ----------------
__global__ __launch_bounds__(64)
void zero_kern(float* __restrict__ p)
{
  p[threadIdx.x] = 0.f;
}

__global__ __launch_bounds__(256)
void absmean4_kern(const float* __restrict__ w0, const float* __restrict__ w1,
                   const float* __restrict__ w2, const float* __restrict__ w3,
                   const long n0, const long n1, const long n2, const long n3,
                   float* __restrict__ acc)
{
  const int t = blockIdx.y;
  const float* w = (t == 0) ? w0 : (t == 1) ? w1 : (t == 2) ? w2 : w3;
  const long  n  = (t == 0) ? n0 : (t == 1) ? n1 : (t == 2) ? n2 : n3;
  const int tid = threadIdx.x;
  float s = 0.f;
  const size_t stride = (size_t)256 * gridDim.x * 4;
  for (size_t i = ((size_t)blockIdx.x * 256 + tid) * 4; i < (size_t)n; i += stride) {
    f32x4 v = *(const f32x4*)(w + i);
    s += fabsf(v[0]) + fabsf(v[1]) + fabsf(v[2]) + fabsf(v[3]);
  }
#pragma unroll
  for (int off = 32; off > 0; off >>= 1) s += __shfl_xor(s, off, 64);
  __shared__ float red[4];
  if ((tid & 63) == 0) red[tid >> 6] = s;
  __syncthreads();
  if (tid == 0) atomicAdd(&acc[t], red[0] + red[1] + red[2] + red[3]);
}

__global__ __launch_bounds__(256)
void quant4_kern(const float* __restrict__ w0, const float* __restrict__ w1,
                 const float* __restrict__ w2, const float* __restrict__ w3,
                 bf16_t* __restrict__ q0, bf16_t* __restrict__ q1,
                 bf16_t* __restrict__ q2, bf16_t* __restrict__ q3,
                 const int n40, const int n41, const int n42, const int n43,
                 const float* __restrict__ acc,
                 const float inv0, const float inv1, const float inv2, const float inv3)
{
  const int t = blockIdx.y;
  const float* w = (t == 0) ? w0 : (t == 1) ? w1 : (t == 2) ? w2 : w3;
  bf16_t*      q = (t == 0) ? q0 : (t == 1) ? q1 : (t == 2) ? q2 : q3;
  const int   n4 = (t == 0) ? n40 : (t == 1) ? n41 : (t == 2) ? n42 : n43;
  const float iv = (t == 0) ? inv0 : (t == 1) ? inv1 : (t == 2) ? inv2 : inv3;
  const int i = blockIdx.x * 256 + threadIdx.x;
  if (i >= n4) return;
  const float s = acc[t] * iv + 1e-8f;
  f32x4 v = ((const f32x4*)w)[i];
  bf16x4 o;
#pragma unroll
  for (int e = 0; e < 4; e++) {
    float qv = rintf(v[e] / s);  // round-half-even, matches jnp.round
    qv = fminf(1.f, fmaxf(-1.f, qv));
    o[e] = (bf16_t)qv;
  }
  ((bf16x4*)q)[i] = o;
}

__global__ __launch_bounds__(256)
void cast4_kern(const float* __restrict__ w0, const float* __restrict__ w1,
                const float* __restrict__ w2, const float* __restrict__ w3,
                bf16_t* __restrict__ q0, bf16_t* __restrict__ q1,
                bf16_t* __restrict__ q2, bf16_t* __restrict__ q3,
                const int n40, const int n41, const int n42, const int n43)
{
  const int t = blockIdx.y;
  const float* w = (t == 0) ? w0 : (t == 1) ? w1 : (t == 2) ? w2 : w3;
  bf16_t*      q = (t == 0) ? q0 : (t == 1) ? q1 : (t == 2) ? q2 : q3;
  const int   n4 = (t == 0) ? n40 : (t == 1) ? n41 : (t == 2) ? n42 : n43;
  const int i = blockIdx.x * 256 + threadIdx.x;
  if (i >= n4) return;
  f32x4 v = ((const f32x4*)w)[i];
  bf16x4 o;
#pragma unroll
  for (int e = 0; e < 4; e++) o[e] = (bf16_t)v[e];
  ((bf16x4*)q)[i] = o;
}

__global__ __launch_bounds__(256)
void copyf_kern(const float* __restrict__ in, float* __restrict__ out, const int n4)
{
  const int i = blockIdx.x * 256 + threadIdx.x;
  if (i < n4) ((f32x4*)out)[i] = ((const f32x4*)in)[i];
}

// ---------------- driver ----------------
extern "C" void kernel_launch(void* const* d_in, const int* in_sizes, int n_in,
                              void* d_out, int out_size, void* d_ws, size_t ws_size,
                              hipStream_t stream)
{
  const float* x     = (const float*)d_in[0];
  const float* ln1_g = (const float*)d_in[1];
  const float* ln1_b = (const float*)d_in[2];
  const float* Wqkv  = (const float*)d_in[3];
  const float* ln2_g = (const float*)d_in[4];
  const float* ln2_b = (const float*)d_in[5];
  const float* Wo    = (const float*)d_in[6];
  const float* bo    = (const float*)d_in[7];
  const float* fg1   = (const float*)d_in[8];
  const float* fb1   = (const float*)d_in[9];
  const float* W1    = (const float*)d_in[10];
  const float* b1    = (const float*)d_in[11];
  const float* fg2   = (const float*)d_in[12];
  const float* fb2   = (const float*)d_in[13];
  const float* W2    = (const float*)d_in[14];
  const float* b2    = (const float*)d_in[15];

  char* ws = (char*)d_ws;
  size_t off = 0;
  float*  sacc  = (float*)(ws + off);  off += 256;                         // scale sums; [63] stays 0
  float*  h     = (float*)(ws + off);  off += (size_t)TOKENS * DIMV * 4;   // 25.2 MB residual stream
  bf16_t* bigA  = (bf16_t*)(ws + off); off += (size_t)TOKENS * MLPW * 2;   // 50.3 MB LN outs / attn out
  bf16_t* bigB  = (bf16_t*)(ws + off); off += (size_t)TOKENS * MLPW * 2;   // 50.3 MB qkv / gelu out
  bf16_t* q_qkv = (bf16_t*)(ws + off); off += (size_t)QKVW * DIMV * 2;
  bf16_t* q_o   = (bf16_t*)(ws + off); off += (size_t)DIMV * INNERV * 2;
  bf16_t* q_1   = (bf16_t*)(ws + off); off += (size_t)MLPW * DIMV * 2;
  bf16_t* q_2   = (bf16_t*)(ws + off); off += (size_t)DIMV * MLPW * 2;     // total ~140 MB

  bf16_t* obuf   = bigA;                              // attn out (12.6 MB)
  bf16_t* ln2out = bigA + (size_t)TOKENS * INNERV;    // LN2 out

  zero_kern<<<1, 64, 0, stream>>>(sacc);
  copyf_kern<<<TOKENS * DIMV / 4 / 256, 256, 0, stream>>>(x, h, TOKENS * DIMV / 4);

  for (int lyr = 0; lyr < 6; ++lyr) {
    const float* wqkv_l = Wqkv + (size_t)lyr * QKVW * DIMV;
    const float* wo_l   = Wo   + (size_t)lyr * DIMV * INNERV;
    const float* w1_l   = W1   + (size_t)lyr * MLPW * DIMV;
    const float* w2_l   = W2   + (size_t)lyr * DIMV * MLPW;
    const float *sq, *so, *s1, *s2p;
    float iq, io, i1, i2, bq, bo2, bb1v, bb2v;
    if (lyr < 5) {
      absmean4_kern<<<dim3(256, 4), 256, 0, stream>>>(
          wqkv_l, wo_l, w1_l, w2_l,
          (long)QKVW * DIMV, (long)DIMV * INNERV, (long)MLPW * DIMV, (long)DIMV * MLPW,
          &sacc[lyr * 4]);
      quant4_kern<<<dim3(MLPW * DIMV / 1024, 4), 256, 0, stream>>>(
          wqkv_l, wo_l, w1_l, w2_l, q_qkv, q_o, q_1, q_2,
          QKVW * DIMV / 4, DIMV * INNERV / 4, MLPW * DIMV / 4, DIMV * MLPW / 4,
          &sacc[lyr * 4],
          1.0f / (QKVW * DIMV), 1.0f / (DIMV * INNERV), 1.0f / (MLPW * DIMV), 1.0f / (DIMV * MLPW));
      sq = &sacc[lyr * 4 + 0]; iq = 1.0f / (QKVW * DIMV); bq = 1e-8f;
      so = &sacc[lyr * 4 + 1]; io = 1.0f / (DIMV * INNERV); bo2 = 1e-8f;
      s1 = &sacc[lyr * 4 + 2]; i1 = 1.0f / (MLPW * DIMV); bb1v = 1e-8f;
      s2p = &sacc[lyr * 4 + 3]; i2 = 1.0f / (DIMV * MLPW); bb2v = 1e-8f;
    } else {
      cast4_kern<<<dim3(MLPW * DIMV / 1024, 4), 256, 0, stream>>>(
          wqkv_l, wo_l, w1_l, w2_l, q_qkv, q_o, q_1, q_2,
          QKVW * DIMV / 4, DIMV * INNERV / 4, MLPW * DIMV / 4, DIMV * MLPW / 4);
      sq = so = s1 = s2p = &sacc[63];  // contains 0
      iq = io = i1 = i2 = 0.f;
      bq = bo2 = bb1v = bb2v = 1.0f;   // s = 0*0 + 1 = 1
    }

    // attention sub-block (grid axes swapped: x = N-panels, y = M-panels)
    ln_kern<float, DIMV><<<TOKENS, 256, 0, stream>>>(h, ln1_g + lyr * DIMV, ln1_b + lyr * DIMV, bigA);
    gemm_nt<128><<<dim3(QKVW / 128, 64), 256, 0, stream>>>(bigA, q_qkv, DIMV, QKVW, EP_STORE, sq, iq, bq, nullptr, nullptr, bigB, nullptr);
    attn_mfma<<<NSEQ / 128 * NH * NB, 512, 0, stream>>>(bigB, obuf);
    ln_kern<bf16_t, INNERV><<<TOKENS, 256, 0, stream>>>(obuf, ln2_g + lyr * INNERV, ln2_b + lyr * INNERV, ln2out);
    gemm_nt<64><<<dim3(DIMV / 128, TOKENS / 64), 256, 0, stream>>>(ln2out, q_o, INNERV, DIMV, EP_BIAS_RES, so, io, bo2, bo + lyr * DIMV, h, nullptr, nullptr);
    // FF sub-block
    ln_kern<float, DIMV><<<TOKENS, 256, 0, stream>>>(h, fg1 + lyr * DIMV, fb1 + lyr * DIMV, bigA);
    gemm_nt<128><<<dim3(MLPW / 128, 64), 256, 0, stream>>>(bigA, q_1, DIMV, MLPW, EP_BIAS_GELU, s1, i1, bb1v, b1 + lyr * MLPW, nullptr, bigB, nullptr);
    ln_kern<bf16_t, MLPW><<<TOKENS, 256, 0, stream>>>(bigB, fg2 + lyr * MLPW, fb2 + lyr * MLPW, bigA);
    // last layer: fuse the residual add + output write (h + v + bias -> d_out)
    gemm_nt<64><<<dim3(DIMV / 128, TOKENS / 64), 256, 0, stream>>>(bigA, q_2, MLPW, DIMV, EP_BIAS_RES, s2p, i2, bb2v, b2 + lyr * DIMV, h, nullptr,
                                                                   (lyr == 5) ? (float*)d_out : nullptr);
  }
}

// Round 20
// 2087.704 us; speedup vs baseline: 1.0376x; 1.0376x over previous
//
#include <hip/hip_runtime.h>
#include <hip/hip_bf16.h>
#include <math.h>

typedef __bf16 bf16_t;
typedef __bf16 bf16x4 __attribute__((ext_vector_type(4)));
typedef __bf16 bf16x8 __attribute__((ext_vector_type(8)));
typedef float  f32x4  __attribute__((ext_vector_type(4)));

#define TOKENS 8192
#define DIMV   768
#define INNERV 768
#define QKVW   2304
#define MLPW   3072
#define NSEQ   1024
#define NB     8
#define NH     12
#define DH     64

enum { EP_STORE = 0, EP_BIAS_RES = 1, EP_BIAS_GELU = 2 };

// async global->LDS DMA, 16B per lane. LDS dest must be wave-uniform base + lane*16.
__device__ __forceinline__ void gload_lds16(const bf16_t* g, bf16_t* l)
{
  __builtin_amdgcn_global_load_lds((const __attribute__((address_space(1))) void*)g,
                                   (__attribute__((address_space(3))) void*)l,
                                   16, 0, 0);
}

// exact-to-1.5e-7 gelu via A&S 7.1.26 erf.
__device__ __forceinline__ float gelu_fast(float x)
{
  const float z = fabsf(x) * 0.70710678118654752f;
  const float d = fmaf(0.3275911f, z, 1.0f);
#if __has_builtin(__builtin_amdgcn_rcpf)
  const float t = __builtin_amdgcn_rcpf(d);
#else
  const float t = 1.0f / d;
#endif
  float p = fmaf(t, 1.061405429f, -1.453152027f);
  p = fmaf(t, p, 1.421413741f);
  p = fmaf(t, p, -0.284496736f);
  p = fmaf(t, p, 0.254829592f);
  p = t * p;
  const float e = __expf(-z * z);
  float erfv = fmaf(-p, e, 1.0f);              // erf(|x|/sqrt(2)), >=0
  erfv = copysignf(erfv, x);
  return 0.5f * x * (1.0f + erfv);
}

// ---------------- GEMM: C[M,N] = s * (A[M,K] * B[N,K]^T) + bias, bf16 in, f32 acc ----
// BMx128 tile, BK=32, triple-buffered LDS, counted-vmcnt 1-barrier pipeline with
// EARLY stage (issue tile t+2 right after the iter-t barrier -> 2 K-steps of cover).
// Coalesced epilogue through aliased LDS.
// Grid ordering: bm = blockIdx.x (FASTEST). r19 lesson: since nbm % 8 == 0, the same
// bm panels revisit the same XCD every bn sweep -> A panels stay L2-resident; the
// swapped ordering re-streamed B (>4MB/XCD) and regressed FETCH 32->54MB. Keep this.
template <int BM>
__global__ __launch_bounds__(256)
void gemm_nt(const bf16_t* __restrict__ A, const bf16_t* __restrict__ B,
             const int K, const int N, const int mode,
             const float* __restrict__ sacc_p, const float sinvn, const float sbias,
             const float* __restrict__ bias,
             float* __restrict__ resid,
             bf16_t* __restrict__ outb,
             float* __restrict__ fout)   // if non-null (EP_BIAS_RES): fout = resid + v + bias
{
  constexpr int MI = BM / 32;            // acc rows of 16x16 frags per wave (4 or 2)
  constexpr int WR = BM / 2;             // wave-tile rows
  __shared__ __align__(16) bf16_t lsAll[3 * BM * 32 + 3 * 128 * 32];
  bf16_t* lsA = lsAll;                   // [3][BM*32]
  bf16_t* lsB = lsAll + 3 * BM * 32;     // [3][128*32]
  const int tid  = threadIdx.x;
  const int lane = tid & 63;
  const int wave = tid >> 6;
  const int wm = wave >> 1, wn = wave & 1;
  const int bm = blockIdx.x, bn = blockIdx.y;

  const int srB   = wave * 32 + (lane >> 2);
  const int fswB  = (srB >> 1) & 3;
  const int scolB = ((lane & 3) ^ fswB) * 8;
  const bf16_t* gB = B + (size_t)(bn * 128 + srB) * K + scolB;
  const int lb0 = srB * 32 + (lane & 3) * 8;
  const int lb1 = (srB + 16) * 32 + (lane & 3) * 8;

  const int srA   = (BM == 128) ? srB : (wave * 16 + (lane >> 2));
  const int fswA  = (srA >> 1) & 3;
  const int scolA = ((lane & 3) ^ fswA) * 8;
  const bf16_t* gA = A + (size_t)(bm * BM + srA) * K + scolA;
  const int la0 = srA * 32 + (lane & 3) * 8;
  const int la1 = (srA + 16) * 32 + (lane & 3) * 8;   // BM==128 only

  f32x4 acc[MI][4];
#pragma unroll
  for (int i = 0; i < MI; i++)
#pragma unroll
    for (int j = 0; j < 4; j++) acc[i][j] = (f32x4){0.f, 0.f, 0.f, 0.f};

  const int fr   = ((lane & 15) >> 1) & 3;
  const int rsl  = ((lane >> 4) ^ fr) * 8;
  const int arow = (wm * WR + (lane & 15)) * 32 + rsl;
  const int brow = (wn * 64 + (lane & 15)) * 32 + rsl;

  auto stage = [&](int b, int kb) {
    gload_lds16(gA + kb, &lsA[b * BM * 32 + la0]);
    if constexpr (BM == 128) gload_lds16(gA + (size_t)16 * K + kb, &lsA[b * BM * 32 + la1]);
    gload_lds16(gB + kb, &lsB[b * 128 * 32 + lb0]);
    gload_lds16(gB + (size_t)16 * K + kb, &lsB[b * 128 * 32 + lb1]);
  };
  auto compute = [&](int b) {
    bf16x8 af[MI], bfv[4];
#pragma unroll
    for (int i = 0; i < MI; i++) af[i]  = *(const bf16x8*)&lsA[b * BM * 32 + arow + i * 16 * 32];
#pragma unroll
    for (int j = 0; j < 4; j++)  bfv[j] = *(const bf16x8*)&lsB[b * 128 * 32 + brow + j * 16 * 32];
#pragma unroll
    for (int i = 0; i < MI; i++)
#pragma unroll
      for (int j = 0; j < 4; j++)
        acc[i][j] = __builtin_amdgcn_mfma_f32_16x16x32_bf16(af[i], bfv[j], acc[i][j], 0, 0, 0);
  };

  const int NT = K / 32;
  stage(0, 0);
  stage(1, 32);
  int cb = 0, sb = 2;
  for (int t = 0; t < NT - 1; ++t) {
    if constexpr (BM == 128) asm volatile("s_waitcnt vmcnt(4)" ::: "memory");
    else                     asm volatile("s_waitcnt vmcnt(3)" ::: "memory");
    __builtin_amdgcn_s_barrier();
    __builtin_amdgcn_sched_barrier(0);                 // nothing hoists above barrier
    if (t + 2 < NT) stage(sb, (t + 2) * 32);           // issue EARLY: 2 K-steps of cover
    compute(cb);
    cb = (cb == 2) ? 0 : cb + 1;
    sb = (sb == 2) ? 0 : sb + 1;
  }
  asm volatile("s_waitcnt vmcnt(0)" ::: "memory");
  __builtin_amdgcn_s_barrier();
  __builtin_amdgcn_sched_barrier(0);
  compute(cb);

  // ---------------- coalesced epilogue via LDS ----------------
  __syncthreads();                       // all waves done with K-loop LDS reads
  const float s = (*sacc_p) * sinvn + sbias;
  const int lr0 = wm * WR + (lane >> 4) * 4;   // local row base of this thread's frags
  const int lc0 = wn * 64 + (lane & 15);       // local col base

  if (mode == EP_BIAS_RES) {
    float* ep = (float*)lsAll;
#pragma unroll
    for (int i = 0; i < MI; i++)
#pragma unroll
      for (int j = 0; j < 4; j++) {
        const float bcol = bias[bn * 128 + lc0 + j * 16];
#pragma unroll
        for (int r = 0; r < 4; r++)
          ep[(lr0 + i * 16 + r) * 132 + lc0 + j * 16] = acc[i][j][r] * s + bcol;
      }
    __syncthreads();
#pragma unroll
    for (int it = 0; it < BM / 8; ++it) {
      const int lr = it * 8 + (tid >> 5);
      const int lc = (tid & 31) * 4;
      f32x4 v = *(const f32x4*)&ep[lr * 132 + lc];
      const size_t idx = (size_t)(bm * BM + lr) * N + bn * 128 + lc;
      f32x4 rv = *(const f32x4*)&resid[idx];
      if (fout) *(f32x4*)&fout[idx]  = rv + v;   // final-layer fused output
      else      *(f32x4*)&resid[idx] = rv + v;
    }
  } else {
    bf16_t* ep = lsAll;
#pragma unroll
    for (int i = 0; i < MI; i++)
#pragma unroll
      for (int j = 0; j < 4; j++) {
        const int col = bn * 128 + lc0 + j * 16;
#pragma unroll
        for (int r = 0; r < 4; r++) {
          const float v = acc[i][j][r] * s;
          ep[(lr0 + i * 16 + r) * 136 + lc0 + j * 16] =
              (mode == EP_STORE) ? (bf16_t)v : (bf16_t)gelu_fast(v + bias[col]);
        }
      }
    __syncthreads();
#pragma unroll
    for (int it = 0; it < BM / 16; ++it) {
      const int lr = it * 16 + (tid >> 4);
      const int lc = (tid & 15) * 8;
      bf16x8 v = *(const bf16x8*)&ep[lr * 136 + lc];
      *(bf16x8*)&outb[(size_t)(bm * BM + lr) * N + bn * 128 + lc] = v;
    }
  }
}

// ---------------- LayerNorm: block-per-row, input register-cached ----------------
template <typename TIN, int W>
__global__ __launch_bounds__(256)
void ln_kern(const TIN* __restrict__ x, const float* __restrict__ g,
             const float* __restrict__ b, bf16_t* __restrict__ y)
{
  constexpr int NV4 = W / 4;                 // vec4s per row (192 or 768)
  constexpr int NV  = (NV4 + 255) / 256;     // vec4s per thread (1 or 3)
  const int row = blockIdx.x;
  const int tid = threadIdx.x;
  const TIN* xr = x + (size_t)row * W;
  f32x4 cache[NV];
  float s = 0.f, s2 = 0.f;
#pragma unroll
  for (int v = 0; v < NV; v++) {
    const int idx = v * 256 + tid;
    if (idx < NV4) {
      f32x4 f;
      if constexpr (sizeof(TIN) == 4) {
        f = ((const f32x4*)xr)[idx];
      } else {
        bf16x4 bv = ((const bf16x4*)xr)[idx];
#pragma unroll
        for (int e = 0; e < 4; e++) f[e] = (float)bv[e];
      }
      cache[v] = f;
#pragma unroll
      for (int e = 0; e < 4; e++) { s += f[e]; s2 += f[e] * f[e]; }
    }
  }
#pragma unroll
  for (int off = 32; off > 0; off >>= 1) {
    s  += __shfl_xor(s,  off, 64);
    s2 += __shfl_xor(s2, off, 64);
  }
  __shared__ float red[8];
  if ((tid & 63) == 0) { red[(tid >> 6) * 2] = s; red[(tid >> 6) * 2 + 1] = s2; }
  __syncthreads();
  const float ts  = red[0] + red[2] + red[4] + red[6];
  const float ts2 = red[1] + red[3] + red[5] + red[7];
  const float invW = 1.0f / (float)W;
  const float mean = ts * invW;
  const float var  = fmaxf(ts2 * invW - mean * mean, 0.f);
  const float rs   = rsqrtf(var + 1e-5f);
  bf16x4* yv = (bf16x4*)(y + (size_t)row * W);
  const f32x4* gv = (const f32x4*)g;
  const f32x4* bv4 = (const f32x4*)b;
#pragma unroll
  for (int v = 0; v < NV; v++) {
    const int idx = v * 256 + tid;
    if (idx < NV4) {
      f32x4 f = cache[v], gg = gv[idx], bb = bv4[idx];
      bf16x4 o;
#pragma unroll
      for (int e = 0; e < 4; e++) o[e] = (bf16_t)((f[e] - mean) * rs * gg[e] + bb[e]);
      yv[idx] = o;
    }
  }
}

// ---------------- MFMA flash attention, 8-wave QBLK=128 ----------------
__global__ __launch_bounds__(512)
void attn_mfma(const bf16_t* __restrict__ qkv, bf16_t* __restrict__ o)
{
  __shared__ __align__(16) bf16_t Ks[64][72];      // K [kv][d], +8 pad
  __shared__ __align__(16) bf16_t Vt[64][72];      // V^T [d][kv], +8 pad
  __shared__ __align__(16) bf16_t Pw[8][16][72];   // per-wave P [q][kv], +8 pad
  const float SCL = 0.125f * 1.44269504088896f;    // scale * log2(e)
  const int tid  = threadIdx.x;
  const int lane = tid & 63;
  const int wave = tid >> 6;                       // 0..7
  const int quad = lane >> 4;
  const int l15  = lane & 15;

  // XCD-aware decomposition (bijective: 768 = 8 * 96)
  const int id      = blockIdx.x;
  const int logical = (id & 7) * 96 + (id >> 3);
  const int qb   = logical & 7;                    // 0..7 (128 q rows each)
  const int rest = logical >> 3;                   // 0..95
  const int hh   = rest % 12;
  const int bb   = rest / 12;
  const size_t tokbase = (size_t)bb * NSEQ;

  const int qrow = qb * 128 + wave * 16 + l15;
  bf16x8 qf[2];
  {
    const bf16_t* qp = qkv + (tokbase + qrow) * QKVW + hh * DH;
    qf[0] = *(const bf16x8*)(qp + quad * 8);
    qf[1] = *(const bf16x8*)(qp + 32 + quad * 8);
  }

  f32x4 Ot[4];
#pragma unroll
  for (int i = 0; i < 4; i++) Ot[i] = (f32x4){0.f, 0.f, 0.f, 0.f};
  float m2[4], lp[4];                // m in log2 units; lp = lane-partial denom
#pragma unroll
  for (int r = 0; r < 4; r++) { m2[r] = -1e30f; lp[r] = 0.f; }

  const int srow = tid & 63;                       // kv row
  const int sd   = (tid >> 6) * 8;                 // d-base (0..56 step 8)

  bf16x8 k0, v0;
  {
    const bf16_t* kp = qkv + (tokbase + srow) * QKVW + INNERV + hh * DH + sd;
    k0 = *(const bf16x8*)kp;
    v0 = *(const bf16x8*)(kp + INNERV);
  }

  for (int kt = 0; kt < NSEQ / 64; ++kt) {
    __syncthreads();                 // all waves done reading prev tile's Ks/Vt
    *(bf16x8*)&Ks[srow][sd] = k0;
#pragma unroll
    for (int e = 0; e < 8; e++) Vt[sd + e][srow] = v0[e];
    __syncthreads();

    // issue next tile's loads NOW — in flight across the whole compute phase (T14)
    bf16x8 nk0 = k0, nv0 = v0;
    if (kt + 1 < NSEQ / 64) {
      const bf16_t* kp = qkv + (tokbase + (kt + 1) * 64 + srow) * QKVW + INNERV + hh * DH + sd;
      nk0 = *(const bf16x8*)kp;
      nv0 = *(const bf16x8*)(kp + INNERV);
    }

    f32x4 st[4];
    __builtin_amdgcn_s_setprio(1);
#pragma unroll
    for (int nt = 0; nt < 4; nt++) {
      bf16x8 b0 = *(const bf16x8*)&Ks[nt * 16 + l15][quad * 8];
      bf16x8 b1 = *(const bf16x8*)&Ks[nt * 16 + l15][32 + quad * 8];
      f32x4 c = (f32x4){0.f, 0.f, 0.f, 0.f};
      c = __builtin_amdgcn_mfma_f32_16x16x32_bf16(qf[0], b0, c, 0, 0, 0);
      c = __builtin_amdgcn_mfma_f32_16x16x32_bf16(qf[1], b1, c, 0, 0, 0);
      st[nt] = c;
    }
    __builtin_amdgcn_s_setprio(0);

    // lane-local maxima; global check via __all (== old global-rmax check)
    float lm[4];
#pragma unroll
    for (int r = 0; r < 4; r++)
      lm[r] = fmaxf(fmaxf(st[0][r], st[1][r]), fmaxf(st[2][r], st[3][r]));
    const bool ok = (lm[0] * SCL <= m2[0] + 8.f) && (lm[1] * SCL <= m2[1] + 8.f) &&
                    (lm[2] * SCL <= m2[2] + 8.f) && (lm[3] * SCL <= m2[3] + 8.f);
    if (!__all(ok)) {                 // slow path: true row-max reduce + rescale
#pragma unroll
      for (int r = 0; r < 4; r++) {
        float v = lm[r];
        v = fmaxf(v, __shfl_xor(v, 1, 64));
        v = fmaxf(v, __shfl_xor(v, 2, 64));
        v = fmaxf(v, __shfl_xor(v, 4, 64));
        v = fmaxf(v, __shfl_xor(v, 8, 64));
        const float rmax2 = v * SCL;
        const float mnew = fmaxf(m2[r], rmax2);
        const float alpha = exp2f(m2[r] - mnew);
        m2[r] = mnew;
        lp[r] *= alpha;
#pragma unroll
        for (int dt = 0; dt < 4; dt++) Ot[dt][r] *= alpha;
      }
    }
#pragma unroll
    for (int nt = 0; nt < 4; nt++) {
#pragma unroll
      for (int r = 0; r < 4; r++) {
        const float p = exp2f(fmaf(st[nt][r], SCL, -m2[r]));
        lp[r] += p;
        Pw[wave][quad * 4 + r][nt * 16 + l15] = (bf16_t)p;
      }
    }

    // Pw slab is WAVE-PRIVATE: own-wave LDS drain suffices (no block barrier).
    asm volatile("s_waitcnt lgkmcnt(0)" ::: "memory");
    __builtin_amdgcn_sched_barrier(0);

    __builtin_amdgcn_s_setprio(1);
#pragma unroll
    for (int kk = 0; kk < 2; kk++) {
      bf16x8 pa = *(const bf16x8*)&Pw[wave][l15][kk * 32 + quad * 8];
#pragma unroll
      for (int dt = 0; dt < 4; dt++) {
        bf16x8 vb = *(const bf16x8*)&Vt[dt * 16 + l15][kk * 32 + quad * 8];
        Ot[dt] = __builtin_amdgcn_mfma_f32_16x16x32_bf16(pa, vb, Ot[dt], 0, 0, 0);
      }
    }
    __builtin_amdgcn_s_setprio(0);

    k0 = nk0; v0 = nv0;
  }

  float inv[4];
#pragma unroll
  for (int r = 0; r < 4; r++) {
    float v = lp[r];
    v += __shfl_xor(v, 1, 64);
    v += __shfl_xor(v, 2, 64);
    v += __shfl_xor(v, 4, 64);
    v += __shfl_xor(v, 8, 64);
    inv[r] = 1.0f / v;
  }
#pragma unroll
  for (int dt = 0; dt < 4; dt++) {
#pragma unroll
    for (int r = 0; r < 4; r++) {
      const int q = qb * 128 + wave * 16 + quad * 4 + r;
      const int d = dt * 16 + l15;
      o[(tokbase + q) * INNERV + hh * DH + d] = (bf16_t)(Ot[dt][r] * inv[r]);
    }
  }
}

// ---------------- ternary quant helpers (f32 weights in), batched x4 ----------------
__global__ __launch_bounds__(64)
void zero_kern(float* __restrict__ p)
{
  p[threadIdx.x] = 0.f;
}

__global__ __launch_bounds__(256)
void absmean4_kern(const float* __restrict__ w0, const float* __restrict__ w1,
                   const float* __restrict__ w2, const float* __restrict__ w3,
                   const long n0, const long n1, const long n2, const long n3,
                   float* __restrict__ acc)
{
  const int t = blockIdx.y;
  const float* w = (t == 0) ? w0 : (t == 1) ? w1 : (t == 2) ? w2 : w3;
  const long  n  = (t == 0) ? n0 : (t == 1) ? n1 : (t == 2) ? n2 : n3;
  const int tid = threadIdx.x;
  float s = 0.f;
  const size_t stride = (size_t)256 * gridDim.x * 4;
  for (size_t i = ((size_t)blockIdx.x * 256 + tid) * 4; i < (size_t)n; i += stride) {
    f32x4 v = *(const f32x4*)(w + i);
    s += fabsf(v[0]) + fabsf(v[1]) + fabsf(v[2]) + fabsf(v[3]);
  }
#pragma unroll
  for (int off = 32; off > 0; off >>= 1) s += __shfl_xor(s, off, 64);
  __shared__ float red[4];
  if ((tid & 63) == 0) red[tid >> 6] = s;
  __syncthreads();
  if (tid == 0) atomicAdd(&acc[t], red[0] + red[1] + red[2] + red[3]);
}

__global__ __launch_bounds__(256)
void quant4_kern(const float* __restrict__ w0, const float* __restrict__ w1,
                 const float* __restrict__ w2, const float* __restrict__ w3,
                 bf16_t* __restrict__ q0, bf16_t* __restrict__ q1,
                 bf16_t* __restrict__ q2, bf16_t* __restrict__ q3,
                 const int n40, const int n41, const int n42, const int n43,
                 const float* __restrict__ acc,
                 const float inv0, const float inv1, const float inv2, const float inv3)
{
  const int t = blockIdx.y;
  const float* w = (t == 0) ? w0 : (t == 1) ? w1 : (t == 2) ? w2 : w3;
  bf16_t*      q = (t == 0) ? q0 : (t == 1) ? q1 : (t == 2) ? q2 : q3;
  const int   n4 = (t == 0) ? n40 : (t == 1) ? n41 : (t == 2) ? n42 : n43;
  const float iv = (t == 0) ? inv0 : (t == 1) ? inv1 : (t == 2) ? inv2 : inv3;
  const int i = blockIdx.x * 256 + threadIdx.x;
  if (i >= n4) return;
  const float s = acc[t] * iv + 1e-8f;
  f32x4 v = ((const f32x4*)w)[i];
  bf16x4 o;
#pragma unroll
  for (int e = 0; e < 4; e++) {
    float qv = rintf(v[e] / s);  // round-half-even, matches jnp.round
    qv = fminf(1.f, fmaxf(-1.f, qv));
    o[e] = (bf16_t)qv;
  }
  ((bf16x4*)q)[i] = o;
}

__global__ __launch_bounds__(256)
void cast4_kern(const float* __restrict__ w0, const float* __restrict__ w1,
                const float* __restrict__ w2, const float* __restrict__ w3,
                bf16_t* __restrict__ q0, bf16_t* __restrict__ q1,
                bf16_t* __restrict__ q2, bf16_t* __restrict__ q3,
                const int n40, const int n41, const int n42, const int n43)
{
  const int t = blockIdx.y;
  const float* w = (t == 0) ? w0 : (t == 1) ? w1 : (t == 2) ? w2 : w3;
  bf16_t*      q = (t == 0) ? q0 : (t == 1) ? q1 : (t == 2) ? q2 : q3;
  const int   n4 = (t == 0) ? n40 : (t == 1) ? n41 : (t == 2) ? n42 : n43;
  const int i = blockIdx.x * 256 + threadIdx.x;
  if (i >= n4) return;
  f32x4 v = ((const f32x4*)w)[i];
  bf16x4 o;
#pragma unroll
  for (int e = 0; e < 4; e++) o[e] = (bf16_t)v[e];
  ((bf16x4*)q)[i] = o;
}

__global__ __launch_bounds__(256)
void copyf_kern(const float* __restrict__ in, float* __restrict__ out, const int n4)
{
  const int i = blockIdx.x * 256 + threadIdx.x;
  if (i < n4) ((f32x4*)out)[i] = ((const f32x4*)in)[i];
}

// ---------------- driver ----------------
extern "C" void kernel_launch(void* const* d_in, const int* in_sizes, int n_in,
                              void* d_out, int out_size, void* d_ws, size_t ws_size,
                              hipStream_t stream)
{
  const float* x     = (const float*)d_in[0];
  const float* ln1_g = (const float*)d_in[1];
  const float* ln1_b = (const float*)d_in[2];
  const float* Wqkv  = (const float*)d_in[3];
  const float* ln2_g = (const float*)d_in[4];
  const float* ln2_b = (const float*)d_in[5];
  const float* Wo    = (const float*)d_in[6];
  const float* bo    = (const float*)d_in[7];
  const float* fg1   = (const float*)d_in[8];
  const float* fb1   = (const float*)d_in[9];
  const float* W1    = (const float*)d_in[10];
  const float* b1    = (const float*)d_in[11];
  const float* fg2   = (const float*)d_in[12];
  const float* fb2   = (const float*)d_in[13];
  const float* W2    = (const float*)d_in[14];
  const float* b2    = (const float*)d_in[15];

  char* ws = (char*)d_ws;
  size_t off = 0;
  float*  sacc  = (float*)(ws + off);  off += 256;                         // scale sums; [63] stays 0
  float*  h     = (float*)(ws + off);  off += (size_t)TOKENS * DIMV * 4;   // 25.2 MB residual stream
  bf16_t* bigA  = (bf16_t*)(ws + off); off += (size_t)TOKENS * MLPW * 2;   // 50.3 MB LN outs / attn out
  bf16_t* bigB  = (bf16_t*)(ws + off); off += (size_t)TOKENS * MLPW * 2;   // 50.3 MB qkv / gelu out
  bf16_t* q_qkv = (bf16_t*)(ws + off); off += (size_t)QKVW * DIMV * 2;
  bf16_t* q_o   = (bf16_t*)(ws + off); off += (size_t)DIMV * INNERV * 2;
  bf16_t* q_1   = (bf16_t*)(ws + off); off += (size_t)MLPW * DIMV * 2;
  bf16_t* q_2   = (bf16_t*)(ws + off); off += (size_t)DIMV * MLPW * 2;     // total ~140 MB

  bf16_t* obuf   = bigA;                              // attn out (12.6 MB)
  bf16_t* ln2out = bigA + (size_t)TOKENS * INNERV;    // LN2 out

  zero_kern<<<1, 64, 0, stream>>>(sacc);
  copyf_kern<<<TOKENS * DIMV / 4 / 256, 256, 0, stream>>>(x, h, TOKENS * DIMV / 4);

  for (int lyr = 0; lyr < 6; ++lyr) {
    const float* wqkv_l = Wqkv + (size_t)lyr * QKVW * DIMV;
    const float* wo_l   = Wo   + (size_t)lyr * DIMV * INNERV;
    const float* w1_l   = W1   + (size_t)lyr * MLPW * DIMV;
    const float* w2_l   = W2   + (size_t)lyr * DIMV * MLPW;
    const float *sq, *so, *s1, *s2p;
    float iq, io, i1, i2, bq, bo2, bb1v, bb2v;
    if (lyr < 5) {
      absmean4_kern<<<dim3(256, 4), 256, 0, stream>>>(
          wqkv_l, wo_l, w1_l, w2_l,
          (long)QKVW * DIMV, (long)DIMV * INNERV, (long)MLPW * DIMV, (long)DIMV * MLPW,
          &sacc[lyr * 4]);
      quant4_kern<<<dim3(MLPW * DIMV / 1024, 4), 256, 0, stream>>>(
          wqkv_l, wo_l, w1_l, w2_l, q_qkv, q_o, q_1, q_2,
          QKVW * DIMV / 4, DIMV * INNERV / 4, MLPW * DIMV / 4, DIMV * MLPW / 4,
          &sacc[lyr * 4],
          1.0f / (QKVW * DIMV), 1.0f / (DIMV * INNERV), 1.0f / (MLPW * DIMV), 1.0f / (DIMV * MLPW));
      sq = &sacc[lyr * 4 + 0]; iq = 1.0f / (QKVW * DIMV); bq = 1e-8f;
      so = &sacc[lyr * 4 + 1]; io = 1.0f / (DIMV * INNERV); bo2 = 1e-8f;
      s1 = &sacc[lyr * 4 + 2]; i1 = 1.0f / (MLPW * DIMV); bb1v = 1e-8f;
      s2p = &sacc[lyr * 4 + 3]; i2 = 1.0f / (DIMV * MLPW); bb2v = 1e-8f;
    } else {
      cast4_kern<<<dim3(MLPW * DIMV / 1024, 4), 256, 0, stream>>>(
          wqkv_l, wo_l, w1_l, w2_l, q_qkv, q_o, q_1, q_2,
          QKVW * DIMV / 4, DIMV * INNERV / 4, MLPW * DIMV / 4, DIMV * MLPW / 4);
      sq = so = s1 = s2p = &sacc[63];  // contains 0
      iq = io = i1 = i2 = 0.f;
      bq = bo2 = bb1v = bb2v = 1.0f;   // s = 0*0 + 1 = 1
    }

    // attention sub-block
    ln_kern<float, DIMV><<<TOKENS, 256, 0, stream>>>(h, ln1_g + lyr * DIMV, ln1_b + lyr * DIMV, bigA);
    gemm_nt<128><<<dim3(64, QKVW / 128), 256, 0, stream>>>(bigA, q_qkv, DIMV, QKVW, EP_STORE, sq, iq, bq, nullptr, nullptr, bigB, nullptr);
    attn_mfma<<<NSEQ / 128 * NH * NB, 512, 0, stream>>>(bigB, obuf);
    ln_kern<bf16_t, INNERV><<<TOKENS, 256, 0, stream>>>(obuf, ln2_g + lyr * INNERV, ln2_b + lyr * INNERV, ln2out);
    gemm_nt<64><<<dim3(TOKENS / 64, DIMV / 128), 256, 0, stream>>>(ln2out, q_o, INNERV, DIMV, EP_BIAS_RES, so, io, bo2, bo + lyr * DIMV, h, nullptr, nullptr);
    // FF sub-block
    ln_kern<float, DIMV><<<TOKENS, 256, 0, stream>>>(h, fg1 + lyr * DIMV, fb1 + lyr * DIMV, bigA);
    gemm_nt<128><<<dim3(64, MLPW / 128), 256, 0, stream>>>(bigA, q_1, DIMV, MLPW, EP_BIAS_GELU, s1, i1, bb1v, b1 + lyr * MLPW, nullptr, bigB, nullptr);
    ln_kern<bf16_t, MLPW><<<TOKENS, 256, 0, stream>>>(bigB, fg2 + lyr * MLPW, fb2 + lyr * MLPW, bigA);
    // last layer: fuse the residual add + output write (h + v + bias -> d_out)
    gemm_nt<64><<<dim3(TOKENS / 64, DIMV / 128), 256, 0, stream>>>(bigA, q_2, MLPW, DIMV, EP_BIAS_RES, s2p, i2, bb2v, b2 + lyr * DIMV, h, nullptr,
                                                                   (lyr == 5) ? (float*)d_out : nullptr);
  }
}